// Round 12
// baseline (236.375 us; speedup 1.0000x reference)
//
#include <hip/hip_runtime.h>

#define NB    16
#define NN    4096
#define NNODE (NB*NN)   // 65536
#define NE    524288

typedef __attribute__((ext_vector_type(8))) short bf16x8_t;
typedef __attribute__((ext_vector_type(4))) float f32x4_t;

__device__ __forceinline__ unsigned short f2bf(float f) {
    union { float f; unsigned u; } v; v.f = f;
    return (unsigned short)((v.u + 0x7FFFu + ((v.u >> 16) & 1u)) >> 16);  // RNE
}
__device__ __forceinline__ float bf2f(unsigned short h) {
    union { unsigned u; float f; } v; v.u = ((unsigned)h) << 16;
    return v.f;
}

// async global->LDS, 16B per lane; LDS dest must be wave-uniform base + lane*16 (linear)
__device__ __forceinline__ void gld16(const void* g, void* l) {
    __builtin_amdgcn_global_load_lds(
        (const __attribute__((address_space(1))) unsigned int*)g,
        (__attribute__((address_space(3))) unsigned int*)l, 16, 0, 0);
}

// ===================== CSR build (by dst) =====================
__global__ void deg_k(const int* __restrict__ adj, const int* __restrict__ ebi, int* __restrict__ deg)
{
    int e = blockIdx.x * 256 + threadIdx.x;
    atomicAdd(&deg[ebi[e] * NN + adj[2 * e + 1]], 1);
}

__global__ void scan_k(const int* __restrict__ deg, int* __restrict__ offs)
{
    __shared__ int sums[1024];
    int t = threadIdx.x;
    int base = t * 64;
    int s = 0;
    for (int i = 0; i < 64; ++i) s += deg[base + i];
    sums[t] = s;
    __syncthreads();
    for (int off = 1; off < 1024; off <<= 1) {
        int add = (t >= off) ? sums[t - off] : 0;
        __syncthreads();
        sums[t] += add;
        __syncthreads();
    }
    int run = (t > 0) ? sums[t - 1] : 0;
    for (int i = 0; i < 64; ++i) { offs[base + i] = run; run += deg[base + i]; }
    if (t == 1023) offs[NNODE] = run;
}

__global__ void scat_k(const int* __restrict__ adj, const int* __restrict__ ebi,
                       const int* __restrict__ offs, int* __restrict__ cur, int* __restrict__ esrc)
{
    int e = blockIdx.x * 256 + threadIdx.x;
    int bb = ebi[e];
    int d = bb * NN + adj[2 * e + 1];
    int s = bb * NN + adj[2 * e + 0];
    esrc[offs[d] + atomicAdd(&cur[d], 1)] = s;
}

// ===================== weight prep (+ zero deg/cur) =====================
__global__ void prep_k(const float* __restrict__ Wm0, const float* __restrict__ Wm1,
                       const float* __restrict__ Wu0, const float* __restrict__ Wu1,
                       const float* __restrict__ Wout,
                       const float* __restrict__ Ws0, const float* __restrict__ Wt0,
                       const float* __restrict__ Ws1, const float* __restrict__ Wt1,
                       const float* __restrict__ Ws2, const float* __restrict__ Wt2,
                       const float* __restrict__ bs0, const float* __restrict__ bt0,
                       const float* __restrict__ bs1, const float* __restrict__ bt1,
                       const float* __restrict__ bs2, const float* __restrict__ bt2,
                       const float* __restrict__ bm0, const float* __restrict__ bm1,
                       unsigned short* __restrict__ Btm0, unsigned short* __restrict__ Btm1,
                       unsigned short* __restrict__ Btu0, unsigned short* __restrict__ Btu1,
                       unsigned short* __restrict__ WoutP,
                       unsigned short* __restrict__ Bt0cat, unsigned short* __restrict__ Bt1cat,
                       unsigned short* __restrict__ Bt2cat,
                       float* __restrict__ b0cat, float* __restrict__ b1cat,
                       float* __restrict__ b2cat,
                       float* __restrict__ bm0cat, float* __restrict__ bm1cat,
                       int* __restrict__ deg, int* __restrict__ cur)
{
    int bid = blockIdx.x, tx = threadIdx.x;
    if (bid < 256) {            // msg: Bt [256][128]
        const float* W = bid < 128 ? Wm0 : Wm1;
        unsigned short* Bt = bid < 128 ? Btm0 : Btm1;
        int idx = (bid & 127) * 256 + tx;
        int n = idx >> 7, k = idx & 127;
        float v = (n < 128) ? W[k * 128 + n] : W[(128 + k) * 128 + (n - 128)];
        Bt[n * 128 + k] = f2bf(v);
    } else if (bid < 512) {     // upd: Bt [128][256]
        const float* W = bid < 384 ? Wu0 : Wu1;
        unsigned short* Bt = bid < 384 ? Btu0 : Btu1;
        int idx = ((bid - 256) & 127) * 256 + tx;
        int n = idx >> 8, k = idx & 255;
        Bt[n * 256 + k] = f2bf(W[k * 128 + n]);
    } else if (bid < 576) {     // WoutP [128][128]
        int idx = (bid - 512) * 256 + tx;
        int n = idx >> 7, k = idx & 127;
        WoutP[n * 128 + k] = f2bf(Wout[k * 128 + n]);
    } else if (bid < 768) {     // L0 cat: [256][192], k<133 real
        int idx = (bid - 576) * 256 + tx;
        int n = idx / 192, kk = idx % 192;
        const float* W = n < 128 ? Ws0 : Wt0;
        int nn = n & 127;
        Bt0cat[n * 192 + kk] = f2bf(kk < 133 ? W[kk * 128 + nn] : 0.f);
    } else if (bid < 896) {     // L1 cat: [256][128]
        int idx = (bid - 768) * 256 + tx;
        int n = idx >> 7, k = idx & 127;
        const float* W = n < 128 ? Ws1 : Wt1;
        Bt1cat[n * 128 + k] = f2bf(W[k * 128 + (n & 127)]);
    } else if (bid < 1024) {    // L2 cat: [256][128], real n in [0,64) and [128,192)
        int idx = (bid - 896) * 256 + tx;
        int n = idx >> 7, k = idx & 127;
        const float* W = n < 128 ? Ws2 : Wt2;
        int nn = n & 127;
        Bt2cat[n * 128 + k] = f2bf(nn < 64 ? W[k * 64 + nn] : 0.f);
    } else if (bid == 1024) {
        b0cat[tx] = (tx < 128) ? bs0[tx] : bt0[tx - 128];
    } else if (bid == 1025) {
        b1cat[tx] = (tx < 128) ? bs1[tx] : bt1[tx - 128];
    } else if (bid == 1026) {
        int nn = tx & 127;
        b2cat[tx] = (nn < 64) ? ((tx < 128) ? bs2[nn] : bt2[nn]) : 0.f;
    } else if (bid == 1027) {
        bm0cat[tx] = (tx < 128) ? 0.f : bm0[tx - 128];
    } else if (bid == 1028) {
        bm1cat[tx] = (tx < 128) ? 0.f : bm1[tx - 128];
    } else {                    // bid 1029..1156: zero deg + cur (int4)
        int idx = (bid - 1029) * 256 + tx;
        int4 z = {0, 0, 0, 0};
        if (idx < 16384) ((int4*)deg)[idx] = z;
        else             ((int4*)cur)[idx - 16384] = z;
    }
}

// ===================== per-block agg gather: P12 -> aggLds (act layout, 256B stride) ========
// aggLds[row][col] = sum_e relu(P1[src_e][col] + P2'[row][col]); bf16, same XOR swizzle as act.
__device__ __forceinline__ void gather_agg(char* aggLds, const unsigned short* __restrict__ P12,
    const int* __restrict__ offs, const int* __restrict__ esrc, size_t row0, int tx)
{
#pragma unroll
    for (int it = 0; it < 4; ++it) {
        int r = it * 16 + (tx >> 4);
        int l = tx & 15;
        size_t node = row0 + r;
        int beg = offs[node], end = offs[node + 1];
        float p2c[8], ac[8];
        {
            uint4 w = *(const uint4*)(P12 + node * 256 + 128 + 8 * l);
            unsigned ww[4] = {w.x, w.y, w.z, w.w};
#pragma unroll
            for (int j = 0; j < 4; ++j) {
                p2c[2*j]   = bf2f((unsigned short)(ww[j] & 0xFFFF));
                p2c[2*j+1] = bf2f((unsigned short)(ww[j] >> 16));
            }
        }
#pragma unroll
        for (int j = 0; j < 8; ++j) ac[j] = 0.f;
        auto accum = [&](uint4 v) {
            unsigned ww[4] = {v.x, v.y, v.z, v.w};
#pragma unroll
            for (int j = 0; j < 4; ++j) {
                ac[2*j]   += fmaxf(bf2f((unsigned short)(ww[j] & 0xFFFF)) + p2c[2*j],   0.f);
                ac[2*j+1] += fmaxf(bf2f((unsigned short)(ww[j] >> 16))    + p2c[2*j+1], 0.f);
            }
        };
        int i = beg;
        for (; i + 3 < end; i += 4) {
            int s0 = esrc[i], s1 = esrc[i+1], s2 = esrc[i+2], s3 = esrc[i+3];
            uint4 v0 = *(const uint4*)(P12 + (size_t)s0 * 256 + 8 * l);
            uint4 v1 = *(const uint4*)(P12 + (size_t)s1 * 256 + 8 * l);
            uint4 v2 = *(const uint4*)(P12 + (size_t)s2 * 256 + 8 * l);
            uint4 v3 = *(const uint4*)(P12 + (size_t)s3 * 256 + 8 * l);
            accum(v0); accum(v1); accum(v2); accum(v3);
        }
        for (; i < end; ++i) {
            uint4 v0 = *(const uint4*)(P12 + (size_t)esrc[i] * 256 + 8 * l);
            accum(v0);
        }
        uint4 o;
        o.x = (unsigned)f2bf(ac[0]) | ((unsigned)f2bf(ac[1]) << 16);
        o.y = (unsigned)f2bf(ac[2]) | ((unsigned)f2bf(ac[3]) << 16);
        o.z = (unsigned)f2bf(ac[4]) | ((unsigned)f2bf(ac[5]) << 16);
        o.w = (unsigned)f2bf(ac[6]) | ((unsigned)f2bf(ac[7]) << 16);
        int cb = l * 16;
        *(uint4*)(aggLds + r * 256 + (cb & ~127) + ((cb & 127) ^ ((r & 7) << 4))) = o;
    }
}

// ===================== msg GEMM phase: LDS-staged B via global_load_lds =====================
__device__ __forceinline__ void msg_phase(const char* act, char* Bs,
    const unsigned short* __restrict__ Bt, const float* __restrict__ bias,
    unsigned short* __restrict__ P12, size_t row0, int tx)
{
    const int wid = tx >> 6, l = tx & 63;
    const int wr = wid >> 1, wc = wid & 1;
    const int rsel = l & 15, kq = l >> 4;
    const int rg = l >> 4, cc = l & 15;
#pragma unroll
    for (int nh = 0; nh < 2; ++nh) {
        f32x4_t acc[2][4];
#pragma unroll
        for (int i = 0; i < 2; ++i)
#pragma unroll
            for (int j = 0; j < 4; ++j) { f32x4_t z = {0.f,0.f,0.f,0.f}; acc[i][j] = z; }
#pragma unroll
        for (int kc = 0; kc < 128; kc += 64) {
            __syncthreads();
#pragma unroll
            for (int p = 0; p < 4; ++p) {
                int idx = tx + p * 256;
                int n = idx >> 3, kg = idx & 7;
                int kgs = kg ^ (n & 7);
                gld16(Bt + (size_t)(nh * 128 + n) * 128 + kc + kgs * 8, Bs + idx * 16);
            }
            __syncthreads();
#pragma unroll
            for (int ks = 0; ks < 2; ++ks) {
                bf16x8_t af[2], bv[4];
#pragma unroll
                for (int fm = 0; fm < 2; ++fm) {
                    int r = wr * 32 + fm * 16 + rsel;
                    af[fm] = *(const bf16x8_t*)(act + r * 256 + kc * 2 + ((ks * 64 + kq * 16) ^ ((r & 7) << 4)));
                }
#pragma unroll
                for (int fn = 0; fn < 4; ++fn) {
                    int n = wc * 64 + fn * 16 + rsel;
                    bv[fn] = *(const bf16x8_t*)(Bs + n * 128 + ((ks * 64 + kq * 16) ^ ((n & 7) << 4)));
                }
#pragma unroll
                for (int fm = 0; fm < 2; ++fm)
#pragma unroll
                    for (int fn = 0; fn < 4; ++fn)
                        acc[fm][fn] = __builtin_amdgcn_mfma_f32_16x16x32_bf16(af[fm], bv[fn], acc[fm][fn], 0, 0, 0);
            }
        }
        __syncthreads();                // all Bs reads done -> reuse as C stage
#pragma unroll
        for (int fm = 0; fm < 2; ++fm)
#pragma unroll
            for (int rr = 0; rr < 4; ++rr) {
                int row = wr * 32 + fm * 16 + rg * 4 + rr;
#pragma unroll
                for (int fn = 0; fn < 4; ++fn) {
                    int col = wc * 64 + fn * 16 + cc;
                    float v = acc[fm][fn][rr] + bias[nh * 128 + col];
                    int cb = col * 2;
                    *(unsigned short*)(Bs + row * 256 + (cb & ~127) + ((cb & 127) ^ ((row & 7) << 4))) = f2bf(v);
                }
            }
        __syncthreads();
#pragma unroll
        for (int p = 0; p < 4; ++p) {
            int idx = tx + p * 256;
            int row = idx >> 4, g = idx & 15;
            int pb = g * 16;
            uint4 v = *(const uint4*)(Bs + row * 256 + (pb & ~127) + ((pb & 127) ^ ((row & 7) << 4)));
            *(uint4*)(P12 + (row0 + row) * 256 + nh * 128 + g * 8) = v;
        }
    }
}

// ===================== fused init + msg0 (XCD-chunked tile swizzle) =====================
__launch_bounds__(256, 4)
__global__ void fused_im_k(const int* __restrict__ types, const float* __restrict__ coords,
                           const unsigned char* __restrict__ maskb,
                           const float* __restrict__ embed, const float* __restrict__ W_in,
                           const float* __restrict__ b_in,
                           const unsigned short* __restrict__ Btm, const float* __restrict__ bmcat,
                           unsigned short* __restrict__ hf, unsigned short* __restrict__ P12)
{
    __shared__ __align__(16) char act[16384];   // 64 x 128 bf16, stride 256B
    __shared__ __align__(16) char Bs[16384];
    const int tx = threadIdx.x;
    const int tile = ((blockIdx.x & 7) * (gridDim.x >> 3)) + (blockIdx.x >> 3);
    const size_t row0 = (size_t)tile * 64;

    float* wf = (float*)Bs;             // [8][128]: rows 0..6 = W_in, row 7 = b_in
    float* xs = (float*)(Bs + 4096);    // [64][8]
#pragma unroll
    for (int p = 0; p < 4; ++p) {
        int idx = tx + p * 256;
        int k = idx >> 7, c = idx & 127;
        wf[idx] = (k < 7) ? W_in[k * 128 + c] : b_in[c];
    }
    if (tx < 64) {
        size_t node = row0 + tx;
        int tp = types[node];
#pragma unroll
        for (int j = 0; j < 4; ++j) xs[tx * 8 + j] = embed[(size_t)tp * 4 + j];
#pragma unroll
        for (int j = 0; j < 3; ++j) xs[tx * 8 + 4 + j] = coords[node * 3 + j];
    }
    __syncthreads();
    {
        int row = tx >> 2, c0 = (tx & 3) * 32;
        float x0 = xs[row*8+0], x1 = xs[row*8+1], x2 = xs[row*8+2], x3 = xs[row*8+3];
        float x4 = xs[row*8+4], x5 = xs[row*8+5], x6 = xs[row*8+6];
        bool msk = maskb[row0 + row];
        int swz = (row & 7) << 4;
#pragma unroll
        for (int c = 0; c < 32; ++c) {
            int col = c0 + c;
            float a = wf[7*128+col] + x0*wf[col] + x1*wf[128+col] + x2*wf[256+col]
                    + x3*wf[384+col] + x4*wf[512+col] + x5*wf[640+col] + x6*wf[768+col];
            a = msk ? 0.f : fmaxf(a, 0.f);
            int cb = col * 2;
            *(unsigned short*)(act + row * 256 + (cb & ~127) + ((cb & 127) ^ swz)) = f2bf(a);
        }
    }
    __syncthreads();
#pragma unroll
    for (int p = 0; p < 4; ++p) {
        int idx = tx + p * 256;
        int row = idx >> 4, g = idx & 15;
        int pb = g * 16;
        uint4 v = *(const uint4*)(act + row * 256 + (pb & ~127) + ((pb & 127) ^ ((row & 7) << 4)));
        *(uint4*)(hf + (row0 + row) * 128 + g * 8) = v;
    }
    msg_phase(act, Bs, Btm, bmcat, P12, row0, tx);
}

// ===================== fused gather+upd+msg (agg_k absorbed) =====================
__launch_bounds__(256, 4)
__global__ void fused_um_k(const unsigned short* __restrict__ hfin,
                           const unsigned short* __restrict__ P12in,
                           const int* __restrict__ offs, const int* __restrict__ esrc,
                           const unsigned short* __restrict__ Btu, const float* __restrict__ bu,
                           const unsigned short* __restrict__ Btm, const float* __restrict__ bmcat,
                           unsigned short* __restrict__ hfout, unsigned short* __restrict__ P12)
{
    __shared__ __align__(16) char act[16384];   // gather: aggLds; later hf_new
    __shared__ __align__(16) char Bs[16384];
    const int tx = threadIdx.x;
    const int wid = tx >> 6, l = tx & 63;
    const int wr = wid >> 1, wc = wid & 1;
    const int rsel = l & 15, kq = l >> 4, rg = l >> 4, cc = l & 15;
    const int tile = ((blockIdx.x & 7) * (gridDim.x >> 3)) + (blockIdx.x >> 3);
    const size_t row0 = (size_t)tile * 64;

    // phase 0: gather agg for my 64 rows into act (aggLds)
    gather_agg(act, P12in, offs, esrc, row0, tx);

    // phase 1: hf_new = relu([hf|aggLds] @ Btu^T + bu)
    f32x4_t acc[2][4];
#pragma unroll
    for (int i = 0; i < 2; ++i)
#pragma unroll
        for (int j = 0; j < 4; ++j) { f32x4_t z = {0.f,0.f,0.f,0.f}; acc[i][j] = z; }
#pragma unroll
    for (int kc = 0; kc < 256; kc += 64) {
        int kloc = kc & 127;
        __syncthreads();   // first iter: aggLds visible; later: prior Bs reads done
#pragma unroll
        for (int p = 0; p < 4; ++p) {
            int idx = tx + p * 256;
            int n = idx >> 3, kg = idx & 7;
            int kgs = kg ^ (n & 7);
            gld16(Btu + (size_t)n * 256 + kc + kgs * 8, Bs + idx * 16);
        }
        __syncthreads();
#pragma unroll
        for (int ks = 0; ks < 2; ++ks) {
            bf16x8_t af[2], bv[4];
#pragma unroll
            for (int fm = 0; fm < 2; ++fm) {
                int r = wr * 32 + fm * 16 + rsel;
                if (kc < 128) {
                    af[fm] = *(const bf16x8_t*)(hfin + (row0 + r) * 128 + kloc + ks * 32 + kq * 8);
                } else {
                    af[fm] = *(const bf16x8_t*)(act + r * 256 + kloc * 2 + ((ks * 64 + kq * 16) ^ ((r & 7) << 4)));
                }
            }
#pragma unroll
            for (int fn = 0; fn < 4; ++fn) {
                int n = wc * 64 + fn * 16 + rsel;
                bv[fn] = *(const bf16x8_t*)(Bs + n * 128 + ((ks * 64 + kq * 16) ^ ((n & 7) << 4)));
            }
#pragma unroll
            for (int fm = 0; fm < 2; ++fm)
#pragma unroll
                for (int fn = 0; fn < 4; ++fn)
                    acc[fm][fn] = __builtin_amdgcn_mfma_f32_16x16x32_bf16(af[fm], bv[fn], acc[fm][fn], 0, 0, 0);
        }
    }
    __syncthreads();       // all aggLds reads done -> safe to overwrite act with hf_new
#pragma unroll
    for (int fm = 0; fm < 2; ++fm)
#pragma unroll
        for (int rr = 0; rr < 4; ++rr) {
            int row = wr * 32 + fm * 16 + rg * 4 + rr;
#pragma unroll
            for (int fn = 0; fn < 4; ++fn) {
                int col = wc * 64 + fn * 16 + cc;
                float v = fmaxf(acc[fm][fn][rr] + bu[col], 0.f);
                int cb = col * 2;
                *(unsigned short*)(act + row * 256 + (cb & ~127) + ((cb & 127) ^ ((row & 7) << 4))) = f2bf(v);
            }
        }
    __syncthreads();
#pragma unroll
    for (int p = 0; p < 4; ++p) {
        int idx = tx + p * 256;
        int row = idx >> 4, g = idx & 15;
        int pb = g * 16;
        uint4 v = *(const uint4*)(act + row * 256 + (pb & ~127) + ((pb & 127) ^ ((row & 7) << 4)));
        *(uint4*)(hfout + (row0 + row) * 128 + g * 8) = v;
    }
    msg_phase(act, Bs, Btm, bmcat, P12, row0, tx);
}

// ===================== fused gather+upd1+out+xfill+MLP+coupling (agg_k absorbed) ============
__launch_bounds__(256, 2)
__global__ void fused_ut_k(const unsigned short* __restrict__ hfin,
                           const unsigned short* __restrict__ P12in,
                           const int* __restrict__ offs, const int* __restrict__ esrc,
                           const unsigned short* __restrict__ Btu, const float* __restrict__ bu,
                           const unsigned short* __restrict__ WoutP, const float* __restrict__ bOut,
                           const unsigned short* __restrict__ Bt0, const float* __restrict__ b0,
                           const unsigned short* __restrict__ Bt1, const float* __restrict__ b1,
                           const unsigned short* __restrict__ Bt2, const float* __restrict__ b2,
                           const float* __restrict__ Ws3, const float* __restrict__ bs3,
                           const float* __restrict__ Wt3, const float* __restrict__ bt3,
                           const float* __restrict__ coords, const int* __restrict__ types,
                           const unsigned char* __restrict__ maskb,
                           float* __restrict__ outc, float* __restrict__ partial)
{
    __shared__ __align__(16) char act[32768];   // [0:16K]=aggLds during ph1; later 64x256 bf16
    __shared__ __align__(16) char hfn[16384];   // 64 x 128 bf16 (later W3/red)
    __shared__ __align__(16) char Bs[32768];    // B staging
    const int tx = threadIdx.x;
    const int wid = tx >> 6, l = tx & 63;
    const int rsel = l & 15, kq = l >> 4, rg = l >> 4, cc = l & 15;
    const int tile = ((blockIdx.x & 7) * (gridDim.x >> 3)) + (blockIdx.x >> 3);
    const size_t row0 = (size_t)tile * 64;
    const int wr = wid >> 1, wc = wid & 1;

    // ---- phase 0: gather agg into act[0:16K] ----
    gather_agg(act, P12in, offs, esrc, row0, tx);

    // ---- phase 1: upd1 -> hfn ([hf|aggLds] @ Btu^T) ----
    {
        f32x4_t acc[2][4];
#pragma unroll
        for (int i = 0; i < 2; ++i)
#pragma unroll
            for (int j = 0; j < 4; ++j) { f32x4_t z = {0.f,0.f,0.f,0.f}; acc[i][j] = z; }
#pragma unroll
        for (int kc = 0; kc < 256; kc += 64) {
            int kloc = kc & 127;
            __syncthreads();   // first iter: aggLds visible
#pragma unroll
            for (int p = 0; p < 4; ++p) {
                int idx = tx + p * 256;
                int n = idx >> 3, kg = idx & 7;
                int kgs = kg ^ (n & 7);
                gld16(Btu + (size_t)n * 256 + kc + kgs * 8, Bs + idx * 16);
            }
            __syncthreads();
#pragma unroll
            for (int ks = 0; ks < 2; ++ks) {
                bf16x8_t af[2], bv[4];
#pragma unroll
                for (int fm = 0; fm < 2; ++fm) {
                    int r = wr * 32 + fm * 16 + rsel;
                    if (kc < 128) {
                        af[fm] = *(const bf16x8_t*)(hfin + (row0 + r) * 128 + kloc + ks * 32 + kq * 8);
                    } else {
                        af[fm] = *(const bf16x8_t*)(act + r * 256 + kloc * 2 + ((ks * 64 + kq * 16) ^ ((r & 7) << 4)));
                    }
                }
#pragma unroll
                for (int fn = 0; fn < 4; ++fn) {
                    int n = wc * 64 + fn * 16 + rsel;
                    bv[fn] = *(const bf16x8_t*)(Bs + n * 128 + ((ks * 64 + kq * 16) ^ ((n & 7) << 4)));
                }
#pragma unroll
                for (int fm = 0; fm < 2; ++fm)
#pragma unroll
                    for (int fn = 0; fn < 4; ++fn)
                        acc[fm][fn] = __builtin_amdgcn_mfma_f32_16x16x32_bf16(af[fm], bv[fn], acc[fm][fn], 0, 0, 0);
            }
        }
#pragma unroll
        for (int fm = 0; fm < 2; ++fm)
#pragma unroll
            for (int rr = 0; rr < 4; ++rr) {
                int row = wr * 32 + fm * 16 + rg * 4 + rr;
#pragma unroll
                for (int fn = 0; fn < 4; ++fn) {
                    int col = wc * 64 + fn * 16 + cc;
                    float v = fmaxf(acc[fm][fn][rr] + bu[col], 0.f);
                    int cb = col * 2;
                    *(unsigned short*)(hfn + row * 256 + (cb & ~127) + ((cb & 127) ^ ((row & 7) << 4))) = f2bf(v);
                }
            }
    }
    __syncthreads();

    // ---- phase 2: node_feats -> act cols 0..127 (mask-zero rows) ----
    {
        f32x4_t acc[2][4];
#pragma unroll
        for (int i = 0; i < 2; ++i)
#pragma unroll
            for (int j = 0; j < 4; ++j) { f32x4_t z = {0.f,0.f,0.f,0.f}; acc[i][j] = z; }
#pragma unroll
        for (int kc = 0; kc < 128; kc += 64) {
            __syncthreads();
#pragma unroll
            for (int p = 0; p < 4; ++p) {
                int idx = tx + p * 256;
                int n = idx >> 3, kg = idx & 7;
                int kgs = kg ^ (n & 7);
                gld16(WoutP + (size_t)n * 128 + kc + kgs * 8, Bs + idx * 16);
            }
            __syncthreads();
#pragma unroll
            for (int ks = 0; ks < 2; ++ks) {
                bf16x8_t af[2], bv[4];
#pragma unroll
                for (int fm = 0; fm < 2; ++fm) {
                    int r = wr * 32 + fm * 16 + rsel;
                    af[fm] = *(const bf16x8_t*)(hfn + r * 256 + kc * 2 + ((ks * 64 + kq * 16) ^ ((r & 7) << 4)));
                }
#pragma unroll
                for (int fn = 0; fn < 4; ++fn) {
                    int n = wc * 64 + fn * 16 + rsel;
                    bv[fn] = *(const bf16x8_t*)(Bs + n * 128 + ((ks * 64 + kq * 16) ^ ((n & 7) << 4)));
                }
#pragma unroll
                for (int fm = 0; fm < 2; ++fm)
#pragma unroll
                    for (int fn = 0; fn < 4; ++fn)
                        acc[fm][fn] = __builtin_amdgcn_mfma_f32_16x16x32_bf16(af[fm], bv[fn], acc[fm][fn], 0, 0, 0);
            }
        }
        __syncthreads();   // aggLds reads (phase 1) + Bs reads done -> safe to overwrite act
#pragma unroll
        for (int fm = 0; fm < 2; ++fm)
#pragma unroll
            for (int rr = 0; rr < 4; ++rr) {
                int row = wr * 32 + fm * 16 + rg * 4 + rr;
                bool zero = maskb[row0 + row];
#pragma unroll
                for (int fn = 0; fn < 4; ++fn) {
                    int col = wc * 64 + fn * 16 + cc;
                    float v = acc[fm][fn][rr] + bOut[col];
                    if (zero) v = 0.f;
                    int cb = col * 2;
                    *(unsigned short*)(act + row * 512 + (cb & ~127) + ((cb & 127) ^ ((row & 7) << 4))) = f2bf(v);
                }
            }
    }
    // ---- xfill: act cols 128..191 ----
#pragma unroll
    for (int p = 0; p < 16; ++p) {
        int idx = tx + p * 256;
        int row = idx >> 6, ci = idx & 63;
        int col = 128 + ci;
        size_t node = row0 + row;
        bool coup = (types[node] > 0) && !maskb[node];
        float v;
        if (ci < 3)       v = coup ? 0.f : coords[node * 3 + ci];
        else if (ci == 3) v = 300.f;
        else if (ci == 4) v = 600.f;
        else              v = 0.f;
        int cb = col * 2;
        *(unsigned short*)(act + row * 512 + (cb & ~127) + ((cb & 127) ^ ((row & 7) << 4))) = f2bf(v);
    }
    __syncthreads();

    // ---- L0 (K=192, N=256), L1, L2 (per-branch K=128, N=256) ----
#pragma unroll
    for (int layer = 0; layer < 3; ++layer) {
        const unsigned short* Bt = layer == 0 ? Bt0 : (layer == 1 ? Bt1 : Bt2);
        const float* bb = layer == 0 ? b0 : (layer == 1 ? b1 : b2);
        const int ldbt = layer == 0 ? 192 : 128;
        const int Ktot = layer == 0 ? 192 : 128;
        const int kbase = (layer == 0) ? 0 : (wc ? 256 : 0);   // branch K offset (bytes)
        f32x4_t acc[2][8];
#pragma unroll
        for (int i = 0; i < 2; ++i)
#pragma unroll
            for (int j = 0; j < 8; ++j) { f32x4_t z = {0.f,0.f,0.f,0.f}; acc[i][j] = z; }
        for (int kc = 0; kc < Ktot; kc += 64) {
            __syncthreads();
#pragma unroll
            for (int p = 0; p < 8; ++p) {
                int idx = tx + p * 256;
                int n = idx >> 3, kg = idx & 7;
                int kgs = kg ^ (n & 7);
                gld16(Bt + (size_t)n * ldbt + kc + kgs * 8, Bs + idx * 16);
            }
            __syncthreads();
#pragma unroll
            for (int ks = 0; ks < 2; ++ks) {
                bf16x8_t af[2], bv[8];
#pragma unroll
                for (int fm = 0; fm < 2; ++fm) {
                    int r = wr * 32 + fm * 16 + rsel;
                    af[fm] = *(const bf16x8_t*)(act + r * 512 + kbase + kc * 2 + ((ks * 64 + kq * 16) ^ ((r & 7) << 4)));
                }
#pragma unroll
                for (int fn = 0; fn < 8; ++fn) {
                    int n = wc * 128 + fn * 16 + rsel;
                    bv[fn] = *(const bf16x8_t*)(Bs + n * 128 + ((ks * 64 + kq * 16) ^ ((n & 7) << 4)));
                }
#pragma unroll
                for (int fm = 0; fm < 2; ++fm)
#pragma unroll
                    for (int fn = 0; fn < 8; ++fn)
                        acc[fm][fn] = __builtin_amdgcn_mfma_f32_16x16x32_bf16(af[fm], bv[fn], acc[fm][fn], 0, 0, 0);
            }
        }
        __syncthreads();               // all act reads done before in-place write
#pragma unroll
        for (int fm = 0; fm < 2; ++fm)
#pragma unroll
            for (int rr = 0; rr < 4; ++rr) {
                int row = wr * 32 + fm * 16 + rg * 4 + rr;
#pragma unroll
                for (int fn = 0; fn < 8; ++fn) {
                    int col = wc * 128 + fn * 16 + cc;
                    float v = fmaxf(acc[fm][fn][rr] + bb[col], 0.f);
                    int cb = col * 2;
                    *(unsigned short*)(act + row * 512 + (cb & ~127) + ((cb & 127) ^ ((row & 7) << 4))) = f2bf(v);
                }
            }
        __syncthreads();
    }

    // ---- L3 (64->3 x2) + coupling + logdet partial ----
    float* W3f = (float*)hfn;                   // [384]
    float* red = (float*)(hfn + 2048);          // [64]
    for (int i = tx; i < 384; i += 256)
        W3f[i] = (i < 192) ? Ws3[i] : Wt3[i - 192];
    __syncthreads();
    {
        int row = tx >> 2, sub = tx & 3;
        int swz = (row & 7) << 4;
        float rs0 = 0.f, rs1 = 0.f, rs2 = 0.f, sh0 = 0.f, sh1 = 0.f, sh2 = 0.f;
#pragma unroll
        for (int kk = 0; kk < 16; ++kk) {
            int k = sub * 16 + kk;
            float av = bf2f(*(const unsigned short*)(act + row * 512 + ((k * 2) ^ swz)));
            float bv = bf2f(*(const unsigned short*)(act + row * 512 + 256 + ((k * 2) ^ swz)));
            rs0 += av * W3f[k * 3 + 0]; rs1 += av * W3f[k * 3 + 1]; rs2 += av * W3f[k * 3 + 2];
            sh0 += bv * W3f[192 + k * 3 + 0]; sh1 += bv * W3f[192 + k * 3 + 1]; sh2 += bv * W3f[192 + k * 3 + 2];
        }
        rs0 += __shfl_xor(rs0, 1); rs0 += __shfl_xor(rs0, 2);
        rs1 += __shfl_xor(rs1, 1); rs1 += __shfl_xor(rs1, 2);
        rs2 += __shfl_xor(rs2, 1); rs2 += __shfl_xor(rs2, 2);
        sh0 += __shfl_xor(sh0, 1); sh0 += __shfl_xor(sh0, 2);
        sh1 += __shfl_xor(sh1, 1); sh1 += __shfl_xor(sh1, 2);
        sh2 += __shfl_xor(sh2, 1); sh2 += __shfl_xor(sh2, 2);
        if (sub == 0) {
            size_t node = row0 + row;
            bool coup = (types[node] > 0) && !maskb[node];
            float c0 = coords[node * 3 + 0], c1 = coords[node * 3 + 1], c2 = coords[node * 3 + 2];
            float ls0 = 0.f, ls1 = 0.f, ls2 = 0.f, o0 = c0, o1 = c1, o2 = c2;
            if (coup) {
                ls0 = tanhf(rs0 + bs3[0]) * 0.5f;
                ls1 = tanhf(rs1 + bs3[1]) * 0.5f;
                ls2 = tanhf(rs2 + bs3[2]) * 0.5f;
                o0 = expf(ls0) * c0 + sh0 + bt3[0];
                o1 = expf(ls1) * c1 + sh1 + bt3[1];
                o2 = expf(ls2) * c2 + sh2 + bt3[2];
            }
            outc[node * 3 + 0] = o0;
            outc[node * 3 + 1] = o1;
            outc[node * 3 + 2] = o2;
            red[row] = ls0 + ls1 + ls2;
        }
    }
    __syncthreads();
    for (int s = 32; s > 0; s >>= 1) {
        if (tx < s) red[tx] += red[tx + s];
        __syncthreads();
    }
    if (tx == 0) partial[tile] = red[0];
}

__global__ void red_k(const float* __restrict__ partial, float* __restrict__ ldet)
{
    __shared__ float s[1024];
    int t = threadIdx.x;
#pragma unroll
    for (int p = 0; p < 4; ++p) s[t + p * 256] = partial[t + p * 256];
    __syncthreads();
    if (t < 16) {
        float v = 0.f;
        for (int i = 0; i < 64; ++i) v += s[t * 64 + i];
        ldet[t] = v;       // 64 tiles x 64 rows = 4096 nodes per batch
    }
}

// ============================================================================================
extern "C" void kernel_launch(void* const* d_in, const int* in_sizes, int n_in,
                              void* d_out, int out_size, void* d_ws, size_t ws_size,
                              hipStream_t stream)
{
    (void)in_sizes; (void)n_in; (void)out_size; (void)ws_size;
    const float* coords = (const float*)d_in[0];
    const int*   types  = (const int*)d_in[1];
    const int*   adj    = (const int*)d_in[2];
    const int*   ebi    = (const int*)d_in[3];
    const unsigned char* maskb = (const unsigned char*)d_in[4];
    const float* embed  = (const float*)d_in[5];
    const float* W_in   = (const float*)d_in[6];
    const float* b_in   = (const float*)d_in[7];
    const float* W_msg[2] = {(const float*)d_in[8],  (const float*)d_in[12]};
    const float* b_msg[2] = {(const float*)d_in[9],  (const float*)d_in[13]};
    const float* W_upd[2] = {(const float*)d_in[10], (const float*)d_in[14]};
    const float* b_upd[2] = {(const float*)d_in[11], (const float*)d_in[15]};
    const float* W_out = (const float*)d_in[16]; const float* b_out = (const float*)d_in[17];
    const float* Ws0 = (const float*)d_in[18]; const float* bs0 = (const float*)d_in[19];
    const float* Ws1 = (const float*)d_in[20]; const float* bs1 = (const float*)d_in[21];
    const float* Ws2 = (const float*)d_in[22]; const float* bs2 = (const float*)d_in[23];
    const float* Ws3 = (const float*)d_in[24]; const float* bs3 = (const float*)d_in[25];
    const float* Wt0 = (const float*)d_in[26]; const float* bt0 = (const float*)d_in[27];
    const float* Wt1 = (const float*)d_in[28]; const float* bt1 = (const float*)d_in[29];
    const float* Wt2 = (const float*)d_in[30]; const float* bt2 = (const float*)d_in[31];
    const float* Wt3 = (const float*)d_in[32]; const float* bt3 = (const float*)d_in[33];

    char* ws = (char*)d_ws;
    size_t off = 0;
    auto alloc = [&](size_t bytes) { void* p = ws + off; off += (bytes + 255) & ~(size_t)255; return p; };
    unsigned short* hf   = (unsigned short*)alloc((size_t)NNODE * 128 * 2);
    unsigned short* P12  = (unsigned short*)alloc((size_t)NNODE * 256 * 2);
    int*   deg  = (int*)alloc((size_t)NNODE * 4);
    int*   offs = (int*)alloc((size_t)(NNODE + 1) * 4);
    int*   cur  = (int*)alloc((size_t)NNODE * 4);
    int*   esrc = (int*)alloc((size_t)NE * 4);
    unsigned short* Btm0 = (unsigned short*)alloc(256 * 128 * 2);
    unsigned short* Btm1 = (unsigned short*)alloc(256 * 128 * 2);
    unsigned short* Btu0 = (unsigned short*)alloc(128 * 256 * 2);
    unsigned short* Btu1 = (unsigned short*)alloc(128 * 256 * 2);
    unsigned short* WoutP  = (unsigned short*)alloc(128 * 128 * 2);
    unsigned short* Bt0cat = (unsigned short*)alloc(256 * 192 * 2);
    unsigned short* Bt1cat = (unsigned short*)alloc(256 * 128 * 2);
    unsigned short* Bt2cat = (unsigned short*)alloc(256 * 128 * 2);
    float* b0cat  = (float*)alloc(256 * 4);
    float* b1cat  = (float*)alloc(256 * 4);
    float* b2cat  = (float*)alloc(256 * 4);
    float* bm0cat = (float*)alloc(256 * 4);
    float* bm1cat = (float*)alloc(256 * 4);
    float* partial = (float*)alloc(1024 * 4);

    prep_k<<<1157, 256, 0, stream>>>(W_msg[0], W_msg[1], W_upd[0], W_upd[1], W_out,
                                     Ws0, Wt0, Ws1, Wt1, Ws2, Wt2,
                                     bs0, bt0, bs1, bt1, bs2, bt2, b_msg[0], b_msg[1],
                                     Btm0, Btm1, Btu0, Btu1, WoutP,
                                     Bt0cat, Bt1cat, Bt2cat,
                                     b0cat, b1cat, b2cat, bm0cat, bm1cat, deg, cur);
    deg_k<<<NE / 256, 256, 0, stream>>>(adj, ebi, deg);
    scan_k<<<1, 1024, 0, stream>>>(deg, offs);
    scat_k<<<NE / 256, 256, 0, stream>>>(adj, ebi, offs, cur, esrc);

    fused_im_k<<<1024, 256, 0, stream>>>(types, coords, maskb, embed, W_in, b_in,
                                         Btm0, bm0cat, hf, P12);
    fused_um_k<<<1024, 256, 0, stream>>>(hf, P12, offs, esrc, Btu0, b_upd[0],
                                         Btm1, bm1cat, hf, P12);
    float* outc = (float*)d_out;
    fused_ut_k<<<1024, 256, 0, stream>>>(hf, P12, offs, esrc, Btu1, b_upd[1], WoutP, b_out,
                                         Bt0cat, b0cat, Bt1cat, b1cat, Bt2cat, b2cat,
                                         Ws3, bs3, Wt3, bt3,
                                         coords, types, maskb, outc, partial);
    red_k<<<1, 256, 0, stream>>>(partial, outc + (size_t)NNODE * 3);
}

// Round 13
// 224.086 us; speedup vs baseline: 1.0548x; 1.0548x over previous
//
#include <hip/hip_runtime.h>

#define NB    16
#define NN    4096
#define NNODE (NB*NN)   // 65536
#define NE    524288

typedef __attribute__((ext_vector_type(8))) short bf16x8_t;
typedef __attribute__((ext_vector_type(4))) float f32x4_t;

__device__ __forceinline__ unsigned short f2bf(float f) {
    union { float f; unsigned u; } v; v.f = f;
    return (unsigned short)((v.u + 0x7FFFu + ((v.u >> 16) & 1u)) >> 16);  // RNE
}
__device__ __forceinline__ float bf2f(unsigned short h) {
    union { unsigned u; float f; } v; v.u = ((unsigned)h) << 16;
    return v.f;
}

// async global->LDS, 16B per lane; LDS dest must be wave-uniform base + lane*16 (linear)
__device__ __forceinline__ void gld16(const void* g, void* l) {
    __builtin_amdgcn_global_load_lds(
        (const __attribute__((address_space(1))) unsigned int*)g,
        (__attribute__((address_space(3))) unsigned int*)l, 16, 0, 0);
}

// ===================== CSR build (by dst) =====================
__global__ void deg_k(const int* __restrict__ adj, const int* __restrict__ ebi, int* __restrict__ deg)
{
    int e = blockIdx.x * 256 + threadIdx.x;
    atomicAdd(&deg[ebi[e] * NN + adj[2 * e + 1]], 1);
}

__global__ void scan_k(const int* __restrict__ deg, int* __restrict__ offs)
{
    __shared__ int sums[1024];
    int t = threadIdx.x;
    int base = t * 64;
    int s = 0;
    for (int i = 0; i < 64; ++i) s += deg[base + i];
    sums[t] = s;
    __syncthreads();
    for (int off = 1; off < 1024; off <<= 1) {
        int add = (t >= off) ? sums[t - off] : 0;
        __syncthreads();
        sums[t] += add;
        __syncthreads();
    }
    int run = (t > 0) ? sums[t - 1] : 0;
    for (int i = 0; i < 64; ++i) { offs[base + i] = run; run += deg[base + i]; }
    if (t == 1023) offs[NNODE] = run;
}

__global__ void scat_k(const int* __restrict__ adj, const int* __restrict__ ebi,
                       const int* __restrict__ offs, int* __restrict__ cur, int* __restrict__ esrc)
{
    int e = blockIdx.x * 256 + threadIdx.x;
    int bb = ebi[e];
    int d = bb * NN + adj[2 * e + 1];
    int s = bb * NN + adj[2 * e + 0];
    esrc[offs[d] + atomicAdd(&cur[d], 1)] = s;
}

// ===================== weight prep (+ zero deg/cur) =====================
__global__ void prep_k(const float* __restrict__ Wm0, const float* __restrict__ Wm1,
                       const float* __restrict__ Wu0, const float* __restrict__ Wu1,
                       const float* __restrict__ Wout,
                       const float* __restrict__ Ws0, const float* __restrict__ Wt0,
                       const float* __restrict__ Ws1, const float* __restrict__ Wt1,
                       const float* __restrict__ Ws2, const float* __restrict__ Wt2,
                       const float* __restrict__ bs0, const float* __restrict__ bt0,
                       const float* __restrict__ bs1, const float* __restrict__ bt1,
                       const float* __restrict__ bs2, const float* __restrict__ bt2,
                       const float* __restrict__ bm0, const float* __restrict__ bm1,
                       unsigned short* __restrict__ Btm0, unsigned short* __restrict__ Btm1,
                       unsigned short* __restrict__ Btu0, unsigned short* __restrict__ Btu1,
                       unsigned short* __restrict__ WoutP,
                       unsigned short* __restrict__ Bt0cat, unsigned short* __restrict__ Bt1cat,
                       unsigned short* __restrict__ Bt2cat,
                       float* __restrict__ b0cat, float* __restrict__ b1cat,
                       float* __restrict__ b2cat,
                       float* __restrict__ bm0cat, float* __restrict__ bm1cat,
                       int* __restrict__ deg, int* __restrict__ cur)
{
    int bid = blockIdx.x, tx = threadIdx.x;
    if (bid < 256) {            // msg: Bt [256][128]
        const float* W = bid < 128 ? Wm0 : Wm1;
        unsigned short* Bt = bid < 128 ? Btm0 : Btm1;
        int idx = (bid & 127) * 256 + tx;
        int n = idx >> 7, k = idx & 127;
        float v = (n < 128) ? W[k * 128 + n] : W[(128 + k) * 128 + (n - 128)];
        Bt[n * 128 + k] = f2bf(v);
    } else if (bid < 512) {     // upd: Bt [128][256]
        const float* W = bid < 384 ? Wu0 : Wu1;
        unsigned short* Bt = bid < 384 ? Btu0 : Btu1;
        int idx = ((bid - 256) & 127) * 256 + tx;
        int n = idx >> 8, k = idx & 255;
        Bt[n * 256 + k] = f2bf(W[k * 128 + n]);
    } else if (bid < 576) {     // WoutP [128][128]
        int idx = (bid - 512) * 256 + tx;
        int n = idx >> 7, k = idx & 127;
        WoutP[n * 128 + k] = f2bf(Wout[k * 128 + n]);
    } else if (bid < 768) {     // L0 cat: [256][192], k<133 real
        int idx = (bid - 576) * 256 + tx;
        int n = idx / 192, kk = idx % 192;
        const float* W = n < 128 ? Ws0 : Wt0;
        int nn = n & 127;
        Bt0cat[n * 192 + kk] = f2bf(kk < 133 ? W[kk * 128 + nn] : 0.f);
    } else if (bid < 896) {     // L1 cat: [256][128]
        int idx = (bid - 768) * 256 + tx;
        int n = idx >> 7, k = idx & 127;
        const float* W = n < 128 ? Ws1 : Wt1;
        Bt1cat[n * 128 + k] = f2bf(W[k * 128 + (n & 127)]);
    } else if (bid < 1024) {    // L2 cat: [256][128], real n in [0,64) and [128,192)
        int idx = (bid - 896) * 256 + tx;
        int n = idx >> 7, k = idx & 127;
        const float* W = n < 128 ? Ws2 : Wt2;
        int nn = n & 127;
        Bt2cat[n * 128 + k] = f2bf(nn < 64 ? W[k * 64 + nn] : 0.f);
    } else if (bid == 1024) {
        b0cat[tx] = (tx < 128) ? bs0[tx] : bt0[tx - 128];
    } else if (bid == 1025) {
        b1cat[tx] = (tx < 128) ? bs1[tx] : bt1[tx - 128];
    } else if (bid == 1026) {
        int nn = tx & 127;
        b2cat[tx] = (nn < 64) ? ((tx < 128) ? bs2[nn] : bt2[nn]) : 0.f;
    } else if (bid == 1027) {
        bm0cat[tx] = (tx < 128) ? 0.f : bm0[tx - 128];
    } else if (bid == 1028) {
        bm1cat[tx] = (tx < 128) ? 0.f : bm1[tx - 128];
    } else {                    // bid 1029..1156: zero deg + cur (int4)
        int idx = (bid - 1029) * 256 + tx;
        int4 z = {0, 0, 0, 0};
        if (idx < 16384) ((int4*)deg)[idx] = z;
        else             ((int4*)cur)[idx - 16384] = z;
    }
}

// ===================== per-block agg gather (256-thread version, for fused_um) ==============
__device__ __forceinline__ void gather_agg(char* aggLds, const unsigned short* __restrict__ P12,
    const int* __restrict__ offs, const int* __restrict__ esrc, size_t row0, int tx)
{
#pragma unroll
    for (int it = 0; it < 4; ++it) {
        int r = it * 16 + (tx >> 4);
        int l = tx & 15;
        size_t node = row0 + r;
        int beg = offs[node], end = offs[node + 1];
        float p2c[8], ac[8];
        {
            uint4 w = *(const uint4*)(P12 + node * 256 + 128 + 8 * l);
            unsigned ww[4] = {w.x, w.y, w.z, w.w};
#pragma unroll
            for (int j = 0; j < 4; ++j) {
                p2c[2*j]   = bf2f((unsigned short)(ww[j] & 0xFFFF));
                p2c[2*j+1] = bf2f((unsigned short)(ww[j] >> 16));
            }
        }
#pragma unroll
        for (int j = 0; j < 8; ++j) ac[j] = 0.f;
        auto accum = [&](uint4 v) {
            unsigned ww[4] = {v.x, v.y, v.z, v.w};
#pragma unroll
            for (int j = 0; j < 4; ++j) {
                ac[2*j]   += fmaxf(bf2f((unsigned short)(ww[j] & 0xFFFF)) + p2c[2*j],   0.f);
                ac[2*j+1] += fmaxf(bf2f((unsigned short)(ww[j] >> 16))    + p2c[2*j+1], 0.f);
            }
        };
        int i = beg;
        for (; i + 3 < end; i += 4) {
            int s0 = esrc[i], s1 = esrc[i+1], s2 = esrc[i+2], s3 = esrc[i+3];
            uint4 v0 = *(const uint4*)(P12 + (size_t)s0 * 256 + 8 * l);
            uint4 v1 = *(const uint4*)(P12 + (size_t)s1 * 256 + 8 * l);
            uint4 v2 = *(const uint4*)(P12 + (size_t)s2 * 256 + 8 * l);
            uint4 v3 = *(const uint4*)(P12 + (size_t)s3 * 256 + 8 * l);
            accum(v0); accum(v1); accum(v2); accum(v3);
        }
        for (; i < end; ++i) {
            uint4 v0 = *(const uint4*)(P12 + (size_t)esrc[i] * 256 + 8 * l);
            accum(v0);
        }
        uint4 o;
        o.x = (unsigned)f2bf(ac[0]) | ((unsigned)f2bf(ac[1]) << 16);
        o.y = (unsigned)f2bf(ac[2]) | ((unsigned)f2bf(ac[3]) << 16);
        o.z = (unsigned)f2bf(ac[4]) | ((unsigned)f2bf(ac[5]) << 16);
        o.w = (unsigned)f2bf(ac[6]) | ((unsigned)f2bf(ac[7]) << 16);
        int cb = l * 16;
        *(uint4*)(aggLds + r * 256 + (cb & ~127) + ((cb & 127) ^ ((r & 7) << 4))) = o;
    }
}

// ===================== msg GEMM phase: LDS-staged B via global_load_lds =====================
__device__ __forceinline__ void msg_phase(const char* act, char* Bs,
    const unsigned short* __restrict__ Bt, const float* __restrict__ bias,
    unsigned short* __restrict__ P12, size_t row0, int tx)
{
    const int wid = tx >> 6, l = tx & 63;
    const int wr = wid >> 1, wc = wid & 1;
    const int rsel = l & 15, kq = l >> 4;
    const int rg = l >> 4, cc = l & 15;
#pragma unroll
    for (int nh = 0; nh < 2; ++nh) {
        f32x4_t acc[2][4];
#pragma unroll
        for (int i = 0; i < 2; ++i)
#pragma unroll
            for (int j = 0; j < 4; ++j) { f32x4_t z = {0.f,0.f,0.f,0.f}; acc[i][j] = z; }
#pragma unroll
        for (int kc = 0; kc < 128; kc += 64) {
            __syncthreads();
#pragma unroll
            for (int p = 0; p < 4; ++p) {
                int idx = tx + p * 256;
                int n = idx >> 3, kg = idx & 7;
                int kgs = kg ^ (n & 7);
                gld16(Bt + (size_t)(nh * 128 + n) * 128 + kc + kgs * 8, Bs + idx * 16);
            }
            __syncthreads();
#pragma unroll
            for (int ks = 0; ks < 2; ++ks) {
                bf16x8_t af[2], bv[4];
#pragma unroll
                for (int fm = 0; fm < 2; ++fm) {
                    int r = wr * 32 + fm * 16 + rsel;
                    af[fm] = *(const bf16x8_t*)(act + r * 256 + kc * 2 + ((ks * 64 + kq * 16) ^ ((r & 7) << 4)));
                }
#pragma unroll
                for (int fn = 0; fn < 4; ++fn) {
                    int n = wc * 64 + fn * 16 + rsel;
                    bv[fn] = *(const bf16x8_t*)(Bs + n * 128 + ((ks * 64 + kq * 16) ^ ((n & 7) << 4)));
                }
#pragma unroll
                for (int fm = 0; fm < 2; ++fm)
#pragma unroll
                    for (int fn = 0; fn < 4; ++fn)
                        acc[fm][fn] = __builtin_amdgcn_mfma_f32_16x16x32_bf16(af[fm], bv[fn], acc[fm][fn], 0, 0, 0);
            }
        }
        __syncthreads();                // all Bs reads done -> reuse as C stage
#pragma unroll
        for (int fm = 0; fm < 2; ++fm)
#pragma unroll
            for (int rr = 0; rr < 4; ++rr) {
                int row = wr * 32 + fm * 16 + rg * 4 + rr;
#pragma unroll
                for (int fn = 0; fn < 4; ++fn) {
                    int col = wc * 64 + fn * 16 + cc;
                    float v = acc[fm][fn][rr] + bias[nh * 128 + col];
                    int cb = col * 2;
                    *(unsigned short*)(Bs + row * 256 + (cb & ~127) + ((cb & 127) ^ ((row & 7) << 4))) = f2bf(v);
                }
            }
        __syncthreads();
#pragma unroll
        for (int p = 0; p < 4; ++p) {
            int idx = tx + p * 256;
            int row = idx >> 4, g = idx & 15;
            int pb = g * 16;
            uint4 v = *(const uint4*)(Bs + row * 256 + (pb & ~127) + ((pb & 127) ^ ((row & 7) << 4)));
            *(uint4*)(P12 + (row0 + row) * 256 + nh * 128 + g * 8) = v;
        }
    }
}

// ===================== fused init + msg0 (XCD-chunked tile swizzle) =====================
__launch_bounds__(256, 4)
__global__ void fused_im_k(const int* __restrict__ types, const float* __restrict__ coords,
                           const unsigned char* __restrict__ maskb,
                           const float* __restrict__ embed, const float* __restrict__ W_in,
                           const float* __restrict__ b_in,
                           const unsigned short* __restrict__ Btm, const float* __restrict__ bmcat,
                           unsigned short* __restrict__ hf, unsigned short* __restrict__ P12)
{
    __shared__ __align__(16) char act[16384];   // 64 x 128 bf16, stride 256B
    __shared__ __align__(16) char Bs[16384];
    const int tx = threadIdx.x;
    const int tile = ((blockIdx.x & 7) * (gridDim.x >> 3)) + (blockIdx.x >> 3);
    const size_t row0 = (size_t)tile * 64;

    float* wf = (float*)Bs;             // [8][128]: rows 0..6 = W_in, row 7 = b_in
    float* xs = (float*)(Bs + 4096);    // [64][8]
#pragma unroll
    for (int p = 0; p < 4; ++p) {
        int idx = tx + p * 256;
        int k = idx >> 7, c = idx & 127;
        wf[idx] = (k < 7) ? W_in[k * 128 + c] : b_in[c];
    }
    if (tx < 64) {
        size_t node = row0 + tx;
        int tp = types[node];
#pragma unroll
        for (int j = 0; j < 4; ++j) xs[tx * 8 + j] = embed[(size_t)tp * 4 + j];
#pragma unroll
        for (int j = 0; j < 3; ++j) xs[tx * 8 + 4 + j] = coords[node * 3 + j];
    }
    __syncthreads();
    {
        int row = tx >> 2, c0 = (tx & 3) * 32;
        float x0 = xs[row*8+0], x1 = xs[row*8+1], x2 = xs[row*8+2], x3 = xs[row*8+3];
        float x4 = xs[row*8+4], x5 = xs[row*8+5], x6 = xs[row*8+6];
        bool msk = maskb[row0 + row];
        int swz = (row & 7) << 4;
#pragma unroll
        for (int c = 0; c < 32; ++c) {
            int col = c0 + c;
            float a = wf[7*128+col] + x0*wf[col] + x1*wf[128+col] + x2*wf[256+col]
                    + x3*wf[384+col] + x4*wf[512+col] + x5*wf[640+col] + x6*wf[768+col];
            a = msk ? 0.f : fmaxf(a, 0.f);
            int cb = col * 2;
            *(unsigned short*)(act + row * 256 + (cb & ~127) + ((cb & 127) ^ swz)) = f2bf(a);
        }
    }
    __syncthreads();
#pragma unroll
    for (int p = 0; p < 4; ++p) {
        int idx = tx + p * 256;
        int row = idx >> 4, g = idx & 15;
        int pb = g * 16;
        uint4 v = *(const uint4*)(act + row * 256 + (pb & ~127) + ((pb & 127) ^ ((row & 7) << 4)));
        *(uint4*)(hf + (row0 + row) * 128 + g * 8) = v;
    }
    msg_phase(act, Bs, Btm, bmcat, P12, row0, tx);
}

// ===================== fused gather+upd+msg (agg absorbed) =====================
__launch_bounds__(256, 4)
__global__ void fused_um_k(const unsigned short* __restrict__ hfin,
                           const unsigned short* __restrict__ P12in,
                           const int* __restrict__ offs, const int* __restrict__ esrc,
                           const unsigned short* __restrict__ Btu, const float* __restrict__ bu,
                           const unsigned short* __restrict__ Btm, const float* __restrict__ bmcat,
                           unsigned short* __restrict__ hfout, unsigned short* __restrict__ P12)
{
    __shared__ __align__(16) char act[16384];   // gather: aggLds; later hf_new
    __shared__ __align__(16) char Bs[16384];
    const int tx = threadIdx.x;
    const int wid = tx >> 6, l = tx & 63;
    const int wr = wid >> 1, wc = wid & 1;
    const int rsel = l & 15, kq = l >> 4, rg = l >> 4, cc = l & 15;
    const int tile = ((blockIdx.x & 7) * (gridDim.x >> 3)) + (blockIdx.x >> 3);
    const size_t row0 = (size_t)tile * 64;

    // phase 0: gather agg for my 64 rows into act (aggLds)
    gather_agg(act, P12in, offs, esrc, row0, tx);

    // phase 1: hf_new = relu([hf|aggLds] @ Btu^T + bu)
    f32x4_t acc[2][4];
#pragma unroll
    for (int i = 0; i < 2; ++i)
#pragma unroll
        for (int j = 0; j < 4; ++j) { f32x4_t z = {0.f,0.f,0.f,0.f}; acc[i][j] = z; }
#pragma unroll
    for (int kc = 0; kc < 256; kc += 64) {
        int kloc = kc & 127;
        __syncthreads();   // first iter: aggLds visible; later: prior Bs reads done
#pragma unroll
        for (int p = 0; p < 4; ++p) {
            int idx = tx + p * 256;
            int n = idx >> 3, kg = idx & 7;
            int kgs = kg ^ (n & 7);
            gld16(Btu + (size_t)n * 256 + kc + kgs * 8, Bs + idx * 16);
        }
        __syncthreads();
#pragma unroll
        for (int ks = 0; ks < 2; ++ks) {
            bf16x8_t af[2], bv[4];
#pragma unroll
            for (int fm = 0; fm < 2; ++fm) {
                int r = wr * 32 + fm * 16 + rsel;
                if (kc < 128) {
                    af[fm] = *(const bf16x8_t*)(hfin + (row0 + r) * 128 + kloc + ks * 32 + kq * 8);
                } else {
                    af[fm] = *(const bf16x8_t*)(act + r * 256 + kloc * 2 + ((ks * 64 + kq * 16) ^ ((r & 7) << 4)));
                }
            }
#pragma unroll
            for (int fn = 0; fn < 4; ++fn) {
                int n = wc * 64 + fn * 16 + rsel;
                bv[fn] = *(const bf16x8_t*)(Bs + n * 128 + ((ks * 64 + kq * 16) ^ ((n & 7) << 4)));
            }
#pragma unroll
            for (int fm = 0; fm < 2; ++fm)
#pragma unroll
                for (int fn = 0; fn < 4; ++fn)
                    acc[fm][fn] = __builtin_amdgcn_mfma_f32_16x16x32_bf16(af[fm], bv[fn], acc[fm][fn], 0, 0, 0);
        }
    }
    __syncthreads();       // all aggLds reads done -> safe to overwrite act with hf_new
#pragma unroll
    for (int fm = 0; fm < 2; ++fm)
#pragma unroll
        for (int rr = 0; rr < 4; ++rr) {
            int row = wr * 32 + fm * 16 + rg * 4 + rr;
#pragma unroll
            for (int fn = 0; fn < 4; ++fn) {
                int col = wc * 64 + fn * 16 + cc;
                float v = fmaxf(acc[fm][fn][rr] + bu[col], 0.f);
                int cb = col * 2;
                *(unsigned short*)(act + row * 256 + (cb & ~127) + ((cb & 127) ^ ((row & 7) << 4))) = f2bf(v);
            }
        }
    __syncthreads();
#pragma unroll
    for (int p = 0; p < 4; ++p) {
        int idx = tx + p * 256;
        int row = idx >> 4, g = idx & 15;
        int pb = g * 16;
        uint4 v = *(const uint4*)(act + row * 256 + (pb & ~127) + ((pb & 127) ^ ((row & 7) << 4)));
        *(uint4*)(hfout + (row0 + row) * 128 + g * 8) = v;
    }
    msg_phase(act, Bs, Btm, bmcat, P12, row0, tx);
}

// ===================== fused gather+upd1+out+xfill+MLP+coupling — 512 threads, 8 waves ======
__launch_bounds__(512, 2)
__global__ void fused_ut_k(const unsigned short* __restrict__ hfin,
                           const unsigned short* __restrict__ P12in,
                           const int* __restrict__ offs, const int* __restrict__ esrc,
                           const unsigned short* __restrict__ Btu, const float* __restrict__ bu,
                           const unsigned short* __restrict__ WoutP, const float* __restrict__ bOut,
                           const unsigned short* __restrict__ Bt0, const float* __restrict__ b0,
                           const unsigned short* __restrict__ Bt1, const float* __restrict__ b1,
                           const unsigned short* __restrict__ Bt2, const float* __restrict__ b2,
                           const float* __restrict__ Ws3, const float* __restrict__ bs3,
                           const float* __restrict__ Wt3, const float* __restrict__ bt3,
                           const float* __restrict__ coords, const int* __restrict__ types,
                           const unsigned char* __restrict__ maskb,
                           float* __restrict__ outc, float* __restrict__ partial)
{
    __shared__ __align__(16) char act[32768];   // [0:16K]=aggLds during ph0/1; later 64x256 bf16
    __shared__ __align__(16) char hfn[16384];   // 64 x 128 bf16 (later W3/red)
    __shared__ __align__(16) char Bs[32768];    // B staging
    const int tx = threadIdx.x;                 // 0..511
    const int wid = tx >> 6, l = tx & 63;
    const int rsel = l & 15, kq = l >> 4, rg = l >> 4, cc = l & 15;
    const int tile = ((blockIdx.x & 7) * (gridDim.x >> 3)) + (blockIdx.x >> 3);
    const size_t row0 = (size_t)tile * 64;
    const int wr = wid >> 2, wc4 = wid & 3;     // 2 row-waves x 4 col-waves

    // ---- phase 0: gather agg into act[0:16K] (2 iters x 32 rows) ----
#pragma unroll
    for (int it = 0; it < 2; ++it) {
        int r = it * 32 + (tx >> 4);
        int ll = tx & 15;
        size_t node = row0 + r;
        int beg = offs[node], end = offs[node + 1];
        float p2c[8], ac[8];
        {
            uint4 w = *(const uint4*)(P12in + node * 256 + 128 + 8 * ll);
            unsigned ww[4] = {w.x, w.y, w.z, w.w};
#pragma unroll
            for (int j = 0; j < 4; ++j) {
                p2c[2*j]   = bf2f((unsigned short)(ww[j] & 0xFFFF));
                p2c[2*j+1] = bf2f((unsigned short)(ww[j] >> 16));
            }
        }
#pragma unroll
        for (int j = 0; j < 8; ++j) ac[j] = 0.f;
        auto accum = [&](uint4 v) {
            unsigned ww[4] = {v.x, v.y, v.z, v.w};
#pragma unroll
            for (int j = 0; j < 4; ++j) {
                ac[2*j]   += fmaxf(bf2f((unsigned short)(ww[j] & 0xFFFF)) + p2c[2*j],   0.f);
                ac[2*j+1] += fmaxf(bf2f((unsigned short)(ww[j] >> 16))    + p2c[2*j+1], 0.f);
            }
        };
        int i = beg;
        for (; i + 3 < end; i += 4) {
            int s0 = esrc[i], s1 = esrc[i+1], s2 = esrc[i+2], s3 = esrc[i+3];
            uint4 v0 = *(const uint4*)(P12in + (size_t)s0 * 256 + 8 * ll);
            uint4 v1 = *(const uint4*)(P12in + (size_t)s1 * 256 + 8 * ll);
            uint4 v2 = *(const uint4*)(P12in + (size_t)s2 * 256 + 8 * ll);
            uint4 v3 = *(const uint4*)(P12in + (size_t)s3 * 256 + 8 * ll);
            accum(v0); accum(v1); accum(v2); accum(v3);
        }
        for (; i < end; ++i) {
            uint4 v0 = *(const uint4*)(P12in + (size_t)esrc[i] * 256 + 8 * ll);
            accum(v0);
        }
        uint4 o;
        o.x = (unsigned)f2bf(ac[0]) | ((unsigned)f2bf(ac[1]) << 16);
        o.y = (unsigned)f2bf(ac[2]) | ((unsigned)f2bf(ac[3]) << 16);
        o.z = (unsigned)f2bf(ac[4]) | ((unsigned)f2bf(ac[5]) << 16);
        o.w = (unsigned)f2bf(ac[6]) | ((unsigned)f2bf(ac[7]) << 16);
        int cb = ll * 16;
        *(uint4*)(act + r * 256 + (cb & ~127) + ((cb & 127) ^ ((r & 7) << 4))) = o;
    }

    // ---- phase 1: upd1 -> hfn ([hf|aggLds] @ Btu^T), M=64 N=128, wave tile 32x32 ----
    {
        f32x4_t acc[2][2];
#pragma unroll
        for (int i = 0; i < 2; ++i)
#pragma unroll
            for (int j = 0; j < 2; ++j) { f32x4_t z = {0.f,0.f,0.f,0.f}; acc[i][j] = z; }
#pragma unroll
        for (int kc = 0; kc < 256; kc += 64) {
            int kloc = kc & 127;
            __syncthreads();
#pragma unroll
            for (int p = 0; p < 2; ++p) {               // stage Btu chunk [128n][64k]
                int idx = tx + p * 512;
                int n = idx >> 3, kg = idx & 7;
                int kgs = kg ^ (n & 7);
                gld16(Btu + (size_t)n * 256 + kc + kgs * 8, Bs + idx * 16);
            }
            __syncthreads();
#pragma unroll
            for (int ks = 0; ks < 2; ++ks) {
                bf16x8_t af[2], bv[2];
#pragma unroll
                for (int fm = 0; fm < 2; ++fm) {
                    int r = wr * 32 + fm * 16 + rsel;
                    if (kc < 128) {
                        af[fm] = *(const bf16x8_t*)(hfin + (row0 + r) * 128 + kloc + ks * 32 + kq * 8);
                    } else {
                        af[fm] = *(const bf16x8_t*)(act + r * 256 + kloc * 2 + ((ks * 64 + kq * 16) ^ ((r & 7) << 4)));
                    }
                }
#pragma unroll
                for (int fn = 0; fn < 2; ++fn) {
                    int n = wc4 * 32 + fn * 16 + rsel;
                    bv[fn] = *(const bf16x8_t*)(Bs + n * 128 + ((ks * 64 + kq * 16) ^ ((n & 7) << 4)));
                }
#pragma unroll
                for (int fm = 0; fm < 2; ++fm)
#pragma unroll
                    for (int fn = 0; fn < 2; ++fn)
                        acc[fm][fn] = __builtin_amdgcn_mfma_f32_16x16x32_bf16(af[fm], bv[fn], acc[fm][fn], 0, 0, 0);
            }
        }
#pragma unroll
        for (int fm = 0; fm < 2; ++fm)
#pragma unroll
            for (int rr = 0; rr < 4; ++rr) {
                int row = wr * 32 + fm * 16 + rg * 4 + rr;
#pragma unroll
                for (int fn = 0; fn < 2; ++fn) {
                    int col = wc4 * 32 + fn * 16 + cc;
                    float v = fmaxf(acc[fm][fn][rr] + bu[col], 0.f);
                    int cb = col * 2;
                    *(unsigned short*)(hfn + row * 256 + (cb & ~127) + ((cb & 127) ^ ((row & 7) << 4))) = f2bf(v);
                }
            }
    }
    __syncthreads();

    // ---- phase 2: node_feats -> act cols 0..127 (mask-zero rows), wave tile 32x32 ----
    {
        f32x4_t acc[2][2];
#pragma unroll
        for (int i = 0; i < 2; ++i)
#pragma unroll
            for (int j = 0; j < 2; ++j) { f32x4_t z = {0.f,0.f,0.f,0.f}; acc[i][j] = z; }
#pragma unroll
        for (int kc = 0; kc < 128; kc += 64) {
            __syncthreads();
#pragma unroll
            for (int p = 0; p < 2; ++p) {               // stage WoutP chunk [128n][64k]
                int idx = tx + p * 512;
                int n = idx >> 3, kg = idx & 7;
                int kgs = kg ^ (n & 7);
                gld16(WoutP + (size_t)n * 128 + kc + kgs * 8, Bs + idx * 16);
            }
            __syncthreads();
#pragma unroll
            for (int ks = 0; ks < 2; ++ks) {
                bf16x8_t af[2], bv[2];
#pragma unroll
                for (int fm = 0; fm < 2; ++fm) {
                    int r = wr * 32 + fm * 16 + rsel;
                    af[fm] = *(const bf16x8_t*)(hfn + r * 256 + kc * 2 + ((ks * 64 + kq * 16) ^ ((r & 7) << 4)));
                }
#pragma unroll
                for (int fn = 0; fn < 2; ++fn) {
                    int n = wc4 * 32 + fn * 16 + rsel;
                    bv[fn] = *(const bf16x8_t*)(Bs + n * 128 + ((ks * 64 + kq * 16) ^ ((n & 7) << 4)));
                }
#pragma unroll
                for (int fm = 0; fm < 2; ++fm)
#pragma unroll
                    for (int fn = 0; fn < 2; ++fn)
                        acc[fm][fn] = __builtin_amdgcn_mfma_f32_16x16x32_bf16(af[fm], bv[fn], acc[fm][fn], 0, 0, 0);
            }
        }
        __syncthreads();   // aggLds reads (phase 1) + Bs reads done -> safe to overwrite act
#pragma unroll
        for (int fm = 0; fm < 2; ++fm)
#pragma unroll
            for (int rr = 0; rr < 4; ++rr) {
                int row = wr * 32 + fm * 16 + rg * 4 + rr;
                bool zero = maskb[row0 + row];
#pragma unroll
                for (int fn = 0; fn < 2; ++fn) {
                    int col = wc4 * 32 + fn * 16 + cc;
                    float v = acc[fm][fn][rr] + bOut[col];
                    if (zero) v = 0.f;
                    int cb = col * 2;
                    *(unsigned short*)(act + row * 512 + (cb & ~127) + ((cb & 127) ^ ((row & 7) << 4))) = f2bf(v);
                }
            }
    }
    // ---- xfill: act cols 128..191 ----
#pragma unroll
    for (int p = 0; p < 8; ++p) {
        int idx = tx + p * 512;
        int row = idx >> 6, ci = idx & 63;
        int col = 128 + ci;
        size_t node = row0 + row;
        bool coup = (types[node] > 0) && !maskb[node];
        float v;
        if (ci < 3)       v = coup ? 0.f : coords[node * 3 + ci];
        else if (ci == 3) v = 300.f;
        else if (ci == 4) v = 600.f;
        else              v = 0.f;
        int cb = col * 2;
        *(unsigned short*)(act + row * 512 + (cb & ~127) + ((cb & 127) ^ ((row & 7) << 4))) = f2bf(v);
    }
    __syncthreads();

    // ---- L0 (K=192, N=256), L1, L2 (per-branch K=128, N=256); wave tile 32x64 ----
#pragma unroll
    for (int layer = 0; layer < 3; ++layer) {
        const unsigned short* Bt = layer == 0 ? Bt0 : (layer == 1 ? Bt1 : Bt2);
        const float* bb = layer == 0 ? b0 : (layer == 1 ? b1 : b2);
        const int ldbt = layer == 0 ? 192 : 128;
        const int Ktot = layer == 0 ? 192 : 128;
        const int kbase = (layer == 0) ? 0 : ((wc4 >= 2) ? 256 : 0);   // branch K offset (bytes)
        f32x4_t acc[2][4];
#pragma unroll
        for (int i = 0; i < 2; ++i)
#pragma unroll
            for (int j = 0; j < 4; ++j) { f32x4_t z = {0.f,0.f,0.f,0.f}; acc[i][j] = z; }
        for (int kc = 0; kc < Ktot; kc += 64) {
            __syncthreads();
#pragma unroll
            for (int p = 0; p < 4; ++p) {               // stage Bt chunk [256n][64k]
                int idx = tx + p * 512;
                int n = idx >> 3, kg = idx & 7;
                int kgs = kg ^ (n & 7);
                gld16(Bt + (size_t)n * ldbt + kc + kgs * 8, Bs + idx * 16);
            }
            __syncthreads();
#pragma unroll
            for (int ks = 0; ks < 2; ++ks) {
                bf16x8_t af[2], bv[4];
#pragma unroll
                for (int fm = 0; fm < 2; ++fm) {
                    int r = wr * 32 + fm * 16 + rsel;
                    af[fm] = *(const bf16x8_t*)(act + r * 512 + kbase + kc * 2 + ((ks * 64 + kq * 16) ^ ((r & 7) << 4)));
                }
#pragma unroll
                for (int fn = 0; fn < 4; ++fn) {
                    int n = wc4 * 64 + fn * 16 + rsel;
                    bv[fn] = *(const bf16x8_t*)(Bs + n * 128 + ((ks * 64 + kq * 16) ^ ((n & 7) << 4)));
                }
#pragma unroll
                for (int fm = 0; fm < 2; ++fm)
#pragma unroll
                    for (int fn = 0; fn < 4; ++fn)
                        acc[fm][fn] = __builtin_amdgcn_mfma_f32_16x16x32_bf16(af[fm], bv[fn], acc[fm][fn], 0, 0, 0);
            }
        }
        __syncthreads();               // all act reads done before in-place write
#pragma unroll
        for (int fm = 0; fm < 2; ++fm)
#pragma unroll
            for (int rr = 0; rr < 4; ++rr) {
                int row = wr * 32 + fm * 16 + rg * 4 + rr;
#pragma unroll
                for (int fn = 0; fn < 4; ++fn) {
                    int col = wc4 * 64 + fn * 16 + cc;
                    float v = fmaxf(acc[fm][fn][rr] + bb[col], 0.f);
                    int cb = col * 2;
                    *(unsigned short*)(act + row * 512 + (cb & ~127) + ((cb & 127) ^ ((row & 7) << 4))) = f2bf(v);
                }
            }
        __syncthreads();
    }

    // ---- L3 (64->3 x2) + coupling + logdet partial (8 threads/row) ----
    float* W3f = (float*)hfn;                   // [384]
    float* red = (float*)(hfn + 2048);          // [64]
    for (int i = tx; i < 384; i += 512)
        W3f[i] = (i < 192) ? Ws3[i] : Wt3[i - 192];
    __syncthreads();
    {
        int row = tx >> 3, sub = tx & 7;
        int swz = (row & 7) << 4;
        float rs0 = 0.f, rs1 = 0.f, rs2 = 0.f, sh0 = 0.f, sh1 = 0.f, sh2 = 0.f;
#pragma unroll
        for (int kk = 0; kk < 8; ++kk) {
            int k = sub * 8 + kk;
            float av = bf2f(*(const unsigned short*)(act + row * 512 + ((k * 2) ^ swz)));
            float bv = bf2f(*(const unsigned short*)(act + row * 512 + 256 + ((k * 2) ^ swz)));
            rs0 += av * W3f[k * 3 + 0]; rs1 += av * W3f[k * 3 + 1]; rs2 += av * W3f[k * 3 + 2];
            sh0 += bv * W3f[192 + k * 3 + 0]; sh1 += bv * W3f[192 + k * 3 + 1]; sh2 += bv * W3f[192 + k * 3 + 2];
        }
        rs0 += __shfl_xor(rs0, 1); rs0 += __shfl_xor(rs0, 2); rs0 += __shfl_xor(rs0, 4);
        rs1 += __shfl_xor(rs1, 1); rs1 += __shfl_xor(rs1, 2); rs1 += __shfl_xor(rs1, 4);
        rs2 += __shfl_xor(rs2, 1); rs2 += __shfl_xor(rs2, 2); rs2 += __shfl_xor(rs2, 4);
        sh0 += __shfl_xor(sh0, 1); sh0 += __shfl_xor(sh0, 2); sh0 += __shfl_xor(sh0, 4);
        sh1 += __shfl_xor(sh1, 1); sh1 += __shfl_xor(sh1, 2); sh1 += __shfl_xor(sh1, 4);
        sh2 += __shfl_xor(sh2, 1); sh2 += __shfl_xor(sh2, 2); sh2 += __shfl_xor(sh2, 4);
        if (sub == 0) {
            size_t node = row0 + row;
            bool coup = (types[node] > 0) && !maskb[node];
            float c0 = coords[node * 3 + 0], c1 = coords[node * 3 + 1], c2 = coords[node * 3 + 2];
            float ls0 = 0.f, ls1 = 0.f, ls2 = 0.f, o0 = c0, o1 = c1, o2 = c2;
            if (coup) {
                ls0 = tanhf(rs0 + bs3[0]) * 0.5f;
                ls1 = tanhf(rs1 + bs3[1]) * 0.5f;
                ls2 = tanhf(rs2 + bs3[2]) * 0.5f;
                o0 = expf(ls0) * c0 + sh0 + bt3[0];
                o1 = expf(ls1) * c1 + sh1 + bt3[1];
                o2 = expf(ls2) * c2 + sh2 + bt3[2];
            }
            outc[node * 3 + 0] = o0;
            outc[node * 3 + 1] = o1;
            outc[node * 3 + 2] = o2;
            red[row] = ls0 + ls1 + ls2;
        }
    }
    __syncthreads();
    for (int s = 32; s > 0; s >>= 1) {
        if (tx < s) red[tx] += red[tx + s];
        __syncthreads();
    }
    if (tx == 0) partial[tile] = red[0];
}

__global__ void red_k(const float* __restrict__ partial, float* __restrict__ ldet)
{
    __shared__ float s[1024];
    int t = threadIdx.x;
#pragma unroll
    for (int p = 0; p < 4; ++p) s[t + p * 256] = partial[t + p * 256];
    __syncthreads();
    if (t < 16) {
        float v = 0.f;
        for (int i = 0; i < 64; ++i) v += s[t * 64 + i];
        ldet[t] = v;       // 64 tiles x 64 rows = 4096 nodes per batch
    }
}

// ============================================================================================
extern "C" void kernel_launch(void* const* d_in, const int* in_sizes, int n_in,
                              void* d_out, int out_size, void* d_ws, size_t ws_size,
                              hipStream_t stream)
{
    (void)in_sizes; (void)n_in; (void)out_size; (void)ws_size;
    const float* coords = (const float*)d_in[0];
    const int*   types  = (const int*)d_in[1];
    const int*   adj    = (const int*)d_in[2];
    const int*   ebi    = (const int*)d_in[3];
    const unsigned char* maskb = (const unsigned char*)d_in[4];
    const float* embed  = (const float*)d_in[5];
    const float* W_in   = (const float*)d_in[6];
    const float* b_in   = (const float*)d_in[7];
    const float* W_msg[2] = {(const float*)d_in[8],  (const float*)d_in[12]};
    const float* b_msg[2] = {(const float*)d_in[9],  (const float*)d_in[13]};
    const float* W_upd[2] = {(const float*)d_in[10], (const float*)d_in[14]};
    const float* b_upd[2] = {(const float*)d_in[11], (const float*)d_in[15]};
    const float* W_out = (const float*)d_in[16]; const float* b_out = (const float*)d_in[17];
    const float* Ws0 = (const float*)d_in[18]; const float* bs0 = (const float*)d_in[19];
    const float* Ws1 = (const float*)d_in[20]; const float* bs1 = (const float*)d_in[21];
    const float* Ws2 = (const float*)d_in[22]; const float* bs2 = (const float*)d_in[23];
    const float* Ws3 = (const float*)d_in[24]; const float* bs3 = (const float*)d_in[25];
    const float* Wt0 = (const float*)d_in[26]; const float* bt0 = (const float*)d_in[27];
    const float* Wt1 = (const float*)d_in[28]; const float* bt1 = (const float*)d_in[29];
    const float* Wt2 = (const float*)d_in[30]; const float* bt2 = (const float*)d_in[31];
    const float* Wt3 = (const float*)d_in[32]; const float* bt3 = (const float*)d_in[33];

    char* ws = (char*)d_ws;
    size_t off = 0;
    auto alloc = [&](size_t bytes) { void* p = ws + off; off += (bytes + 255) & ~(size_t)255; return p; };
    unsigned short* hf   = (unsigned short*)alloc((size_t)NNODE * 128 * 2);
    unsigned short* P12  = (unsigned short*)alloc((size_t)NNODE * 256 * 2);
    int*   deg  = (int*)alloc((size_t)NNODE * 4);
    int*   offs = (int*)alloc((size_t)(NNODE + 1) * 4);
    int*   cur  = (int*)alloc((size_t)NNODE * 4);
    int*   esrc = (int*)alloc((size_t)NE * 4);
    unsigned short* Btm0 = (unsigned short*)alloc(256 * 128 * 2);
    unsigned short* Btm1 = (unsigned short*)alloc(256 * 128 * 2);
    unsigned short* Btu0 = (unsigned short*)alloc(128 * 256 * 2);
    unsigned short* Btu1 = (unsigned short*)alloc(128 * 256 * 2);
    unsigned short* WoutP  = (unsigned short*)alloc(128 * 128 * 2);
    unsigned short* Bt0cat = (unsigned short*)alloc(256 * 192 * 2);
    unsigned short* Bt1cat = (unsigned short*)alloc(256 * 128 * 2);
    unsigned short* Bt2cat = (unsigned short*)alloc(256 * 128 * 2);
    float* b0cat  = (float*)alloc(256 * 4);
    float* b1cat  = (float*)alloc(256 * 4);
    float* b2cat  = (float*)alloc(256 * 4);
    float* bm0cat = (float*)alloc(256 * 4);
    float* bm1cat = (float*)alloc(256 * 4);
    float* partial = (float*)alloc(1024 * 4);

    prep_k<<<1157, 256, 0, stream>>>(W_msg[0], W_msg[1], W_upd[0], W_upd[1], W_out,
                                     Ws0, Wt0, Ws1, Wt1, Ws2, Wt2,
                                     bs0, bt0, bs1, bt1, bs2, bt2, b_msg[0], b_msg[1],
                                     Btm0, Btm1, Btu0, Btu1, WoutP,
                                     Bt0cat, Bt1cat, Bt2cat,
                                     b0cat, b1cat, b2cat, bm0cat, bm1cat, deg, cur);
    deg_k<<<NE / 256, 256, 0, stream>>>(adj, ebi, deg);
    scan_k<<<1, 1024, 0, stream>>>(deg, offs);
    scat_k<<<NE / 256, 256, 0, stream>>>(adj, ebi, offs, cur, esrc);

    fused_im_k<<<1024, 256, 0, stream>>>(types, coords, maskb, embed, W_in, b_in,
                                         Btm0, bm0cat, hf, P12);
    fused_um_k<<<1024, 256, 0, stream>>>(hf, P12, offs, esrc, Btu0, b_upd[0],
                                         Btm1, bm1cat, hf, P12);
    float* outc = (float*)d_out;
    fused_ut_k<<<1024, 512, 0, stream>>>(hf, P12, offs, esrc, Btu1, b_upd[1], WoutP, b_out,
                                         Bt0cat, b0cat, Bt1cat, b1cat, Bt2cat, b2cat,
                                         Ws3, bs3, Wt3, bt3,
                                         coords, types, maskb, outc, partial);
    red_k<<<1, 256, 0, stream>>>(partial, outc + (size_t)NNODE * 3);
}